// Round 9
// baseline (445.248 us; speedup 1.0000x reference)
//
#include <hip/hip_runtime.h>

#define HID 64
#define VOC 64
#define NSLOT 8
#define NB 256
#define SEQL 2048
#define NT 512            // 8 waves; wave w computes vocab rows w*8..w*8+7
#define HPAD 65           // hlds pitch: conflict-free

// ---------------------------------------------------------------------------
// memset(4B) + single kernel, 256 blocks x 512 threads. NO cross-block sync
// (r3/r6/r7/r8 lesson: agent-scope release/acquire = L2 writeback/invalidate
// storm on non-coherent XCDs, 30-200us). Each block redundantly computes the
// 64-row vocab table with the r2/r4-PROVEN fast shape:
//   - broadcasts via fully-unrolled __shfl(x, CONST) -> v_readlane (VALU),
//     NOT runtime-index ds_bpermute (r7 mistake);
//   - weights via per-lane coalesced global loads -> vmcnt-pipelined VMEM,
//     NOT wave-uniform s_load -> lgkmcnt serialization (r5/r6 mistake);
//   - 8 rows per wave so each weight load feeds 16 FMAs (L2 BW amortized);
//   - q computed only for this block's last token (not the 64x64 table).
// Then: histogram (overlapped) -> rank -> greedy top-8 multiset -> attention
// -> entropy gate -> logits. Entropy mean: one memory-side atomicAdd per
// block into out[16384], zeroed by the preceding 4-byte memset node
// (r4-proven primitive; no fences, no spins).
// ---------------------------------------------------------------------------
__global__ __launch_bounds__(NT) void fused_kernel(
    const int* __restrict__ seq,
    const float* __restrict__ embed, const float* __restrict__ w1, const float* __restrict__ b1,
    const float* __restrict__ w2, const float* __restrict__ b2,
    const float* __restrict__ ln_g, const float* __restrict__ ln_b,
    const float* __restrict__ gate_w, const float* __restrict__ gate_b,
    const float* __restrict__ q_w, const float* __restrict__ q_b,
    const float* __restrict__ out_w, const float* __restrict__ out_b,
    float* __restrict__ out, float* __restrict__ ent_out)
{
    __shared__ float hlds[VOC * HPAD];   // h rows, padded: conflict-free
    __shared__ float sscore[VOC];
    __shared__ int   sorder[VOC];
    __shared__ int   hist[VOC];
    __shared__ float sqv[HID];
    __shared__ float sctx[HID];
    __shared__ int   svids[NSLOT];
    __shared__ float sla[NSLOT];
    __shared__ float seff[NSLOT];
    __shared__ int   shvlast;

    const int t = threadIdx.x;
    const int b = blockIdx.x;
    const int lane = t & 63;
    const int wave = t >> 6;

    // Own seq row: 2048 ints = 512 int4, one per thread.
    const int4 a = ((const int4*)(seq + (size_t)b * SEQL))[t];
    if (t < VOC) hist[t] = 0;
    if (t == NT - 1) shvlast = a.w;      // seq[b][2047]
    __syncthreads();

    // Histogram (LDS atomics; overlaps the FFN below -- no barrier between).
    atomicAdd(&hist[a.x], 1);
    atomicAdd(&hist[a.y], 1);
    atomicAdd(&hist[a.z], 1);
    atomicAdd(&hist[a.w], 1);

    // ---- redundant vocab table: wave computes rows r0..r0+7 ---------------
    {
        const int r0 = wave * 8;
        float e[8];
#pragma unroll
        for (int r = 0; r < 8; ++r) e[r] = embed[(r0 + r) * HID + lane];

        // FFN1: lane = hidden units (lane, lane+64); 8 rows share weights.
        float fa[8], fb[8];
        const float b1a = b1[lane], b1b = b1[HID + lane];
#pragma unroll
        for (int r = 0; r < 8; ++r) { fa[r] = b1a; fb[r] = b1b; }
#pragma unroll
        for (int i = 0; i < HID; ++i) {              // FULL unroll: readlane
            const float wa = w1[i * 2 * HID + lane];
            const float wb = w1[i * 2 * HID + HID + lane];
#pragma unroll
            for (int r = 0; r < 8; ++r) {
                const float ei = __shfl(e[r], i);    // const lane -> readlane
                fa[r] = fmaf(ei, wa, fa[r]);
                fb[r] = fmaf(ei, wb, fb[r]);
            }
        }
#pragma unroll
        for (int r = 0; r < 8; ++r) {
            fa[r] = fmaxf(fa[r], 0.0f);
            fb[r] = fmaxf(fb[r], 0.0f);
        }

        // FFN2 + residual: lane = output unit i.
        float z[8];
        const float b2v = b2[lane];
#pragma unroll
        for (int r = 0; r < 8; ++r) z[r] = e[r] + b2v;
#pragma unroll
        for (int j = 0; j < HID; ++j) {              // FULL unroll: readlane
            const float wva = w2[j * HID + lane];
            const float wvb = w2[(HID + j) * HID + lane];
#pragma unroll
            for (int r = 0; r < 8; ++r) {
                z[r] = fmaf(__shfl(fa[r], j), wva, z[r]);
                z[r] = fmaf(__shfl(fb[r], j), wvb, z[r]);
            }
        }

        // LayerNorm + gate score per row (wave butterflies).
        const float lng = ln_g[lane], lnb = ln_b[lane], gwv = gate_w[lane];
        const float gbv = gate_b[0];
#pragma unroll
        for (int r = 0; r < 8; ++r) {
            float s = z[r];
#pragma unroll
            for (int m = 32; m; m >>= 1) s += __shfl_xor(s, m);
            const float mu = s * (1.0f / HID);
            const float d = z[r] - mu;
            float vs = d * d;
#pragma unroll
            for (int m = 32; m; m >>= 1) vs += __shfl_xor(vs, m);
            const float inv = 1.0f / sqrtf(vs * (1.0f / HID) + 1e-5f);
            const float h = d * inv * lng + lnb;
            hlds[(r0 + r) * HPAD + lane] = h;
            float sc = h * gwv;
#pragma unroll
            for (int m = 32; m; m >>= 1) sc += __shfl_xor(sc, m);
            if (lane == 0) sscore[r0 + r] = sc + gbv;
        }
    }
    __syncthreads();                      // h, scores, histogram all ready

    // ---- rank ids (t<64) ; q row of own last token (t in [64,128)) --------
    if (t < VOC) {
        const float sv = sscore[t];
        int r = 0;
        for (int u = 0; u < VOC; ++u) {
            const float su = sscore[u];
            if (su > sv || (su == sv && u < t)) ++r;
        }
        sorder[r] = t;
    } else if (t < 2 * VOC) {
        const int i = t - VOC;
        const int vl = shvlast;
        float qa = q_b[i];
#pragma unroll 8
        for (int k = 0; k < HID; ++k)     // hlds[vl][k]: broadcast ds_read
            qa = fmaf(hlds[vl * HPAD + k], q_w[k * HID + i], qa);
        sqv[i] = qa;
    }
    __syncthreads();

    // ---- greedy top-8 multiset by descending score with multiplicity ------
    if (t == 0) {
        int r = NSLOT, n = 0, pos = 0;
        while (r > 0) {
            const int v = sorder[pos++];
            int c = hist[v];
            if (c > r) c = r;
            for (int k = 0; k < c; ++k) svids[n++] = v;
            r -= c;
        }
    }
    __syncthreads();

    // ---- attention logits: 8 lanes per slot, 3-step shfl reduce -----------
    if (t < VOC) {
        const int k = t >> 3, e2 = t & 7;
        const float* hr = &hlds[svids[k] * HPAD];
        float p = 0.0f;
#pragma unroll
        for (int m = 0; m < 8; ++m)
            p = fmaf(hr[e2 + 8 * m], sqv[e2 + 8 * m], p);
        p += __shfl_xor(p, 1);
        p += __shfl_xor(p, 2);
        p += __shfl_xor(p, 4);
        if (e2 == 0) sla[k] = p * 0.125f; // 1/sqrt(64)
    }
    __syncthreads();

    // ---- softmax + entropy gate; memory-side atomicAdd for the mean -------
    if (t == 0) {
        float m = -1e30f;
        for (int k = 0; k < NSLOT; ++k) m = fmaxf(m, sla[k]);
        float e2[NSLOT], s = 0.0f;
        for (int k = 0; k < NSLOT; ++k) { e2[k] = expf(sla[k] - m); s += e2[k]; }
        const float invs = 1.0f / s;
        float ent = 0.0f;
        for (int k = 0; k < NSLOT; ++k) {
            const float av = e2[k] * invs;
            ent -= av * logf(av + 1e-9f);
        }
        const float high = (ent > 1.5f) ? 1.0f : 0.0f;
        for (int k = 0; k < NSLOT; ++k)
            seff[k] = (1.0f - high) * (e2[k] * invs) + high * (1.0f / NSLOT);
        atomicAdd(ent_out, ent * (1.0f / NB));
    }
    __syncthreads();

    // ---- ctx then logits --------------------------------------------------
    if (t < HID) {
        float cx = 0.0f;
#pragma unroll
        for (int k = 0; k < NSLOT; ++k)
            cx = fmaf(seff[k], hlds[svids[k] * HPAD + t], cx);
        sctx[t] = cx;
    }
    __syncthreads();
    if (t < VOC) {
        float o = out_b[t];
#pragma unroll 8
        for (int i = 0; i < HID; ++i)
            o = fmaf(sctx[i], out_w[i * VOC + t], o);
        out[(size_t)b * VOC + t] = o;
    }
}

extern "C" void kernel_launch(void* const* d_in, const int* in_sizes, int n_in,
                              void* d_out, int out_size, void* d_ws, size_t ws_size,
                              hipStream_t stream) {
    const int*   seq    = (const int*)  d_in[0];
    const float* embed  = (const float*)d_in[1];
    const float* w1     = (const float*)d_in[2];
    const float* b1     = (const float*)d_in[3];
    const float* w2     = (const float*)d_in[4];
    const float* b2     = (const float*)d_in[5];
    const float* ln_g   = (const float*)d_in[6];
    const float* ln_b   = (const float*)d_in[7];
    const float* gate_w = (const float*)d_in[8];
    const float* gate_b = (const float*)d_in[9];
    const float* q_w    = (const float*)d_in[10];
    const float* q_b    = (const float*)d_in[11];
    const float* out_w  = (const float*)d_in[12];
    const float* out_b  = (const float*)d_in[13];
    float* out = (float*)d_out;
    float* ent_out = out + (size_t)NB * VOC;

    hipMemsetAsync(ent_out, 0, sizeof(float), stream);
    fused_kernel<<<NB, NT, 0, stream>>>(seq, embed, w1, b1, w2, b2,
                                        ln_g, ln_b, gate_w, gate_b,
                                        q_w, q_b, out_w, out_b,
                                        out, ent_out);
}